// Round 3
// baseline (417.027 us; speedup 1.0000x reference)
//
#include <hip/hip_runtime.h>

#define N_NODES 262144
#define BGRAPHS 1024
#define NPG 256
#define LATENT 256
#define HIDDEN 512
#define BM 128

typedef unsigned short ushort_t;
typedef __attribute__((ext_vector_type(4))) float  f32x4;
typedef __attribute__((ext_vector_type(8))) short  short8;
typedef __attribute__((ext_vector_type(4))) int    int4v;
typedef __attribute__((ext_vector_type(2))) unsigned int uint2v;
typedef __attribute__((ext_vector_type(4))) float  float4v;

__device__ __forceinline__ unsigned int f2bf(float f) {
  union { float f; unsigned int u; } v; v.f = f;
  unsigned int u = v.u;
  return (u + 0x7fffu + ((u >> 16) & 1u)) >> 16;
}
__device__ __forceinline__ float silu_f(float x) { return x / (1.0f + __expf(-x)); }

// ---------------------------------------------------------------------------
// Weight prep: pre-tile W0/W1 (f32, k-major [K][N]) into the per-K-step LDS
// image: per K-step (BK=32) a contiguous 32 KB block [slot 0..3][n 0..511][8
// bf16], slot = k-octet within step. Linear (no bake needed; W fragment reads
// are per-quarter conflict-free).
// ---------------------------------------------------------------------------
__global__ void prep_weights(const float* __restrict__ W0, const float* __restrict__ W1,
                             ushort_t* __restrict__ W0pre, ushort_t* __restrict__ W1pre) {
  int c = blockIdx.x * 256 + threadIdx.x;
  const int C0 = (HIDDEN * LATENT) / 8;   // 16384 cells
  const float* src;
  ushort_t* dst;
  int cc;
  if (c < C0) { src = W0; dst = W0pre; cc = c; }
  else        { src = W1; dst = W1pre; cc = c - C0; }
  int kstep = cc >> 11;
  int slot = (cc >> 9) & 3;
  int n = cc & 511;
  int kb = kstep * 32 + slot * 8;
  unsigned int w[4];
#pragma unroll
  for (int j = 0; j < 4; ++j) {
    unsigned lo = f2bf(src[(size_t)(kb + 2 * j) * HIDDEN + n]);
    unsigned hi = f2bf(src[(size_t)(kb + 2 * j + 1) * HIDDEN + n]);
    w[j] = lo | (hi << 16);
  }
  *(int4v*)(dst + (size_t)cc * 8) = *(int4v*)w;
}

// ---------------------------------------------------------------------------
// Fused MLP: per block M=128 rows, full N=512. h1 stays in LDS (128 KB).
// Weights single-buffered (32 KB) with register prefetch one K-step ahead.
// ---------------------------------------------------------------------------
__global__ __launch_bounds__(512, 2) void fused_mlp(
    const float* __restrict__ feat, const ushort_t* __restrict__ W0pre,
    const ushort_t* __restrict__ W1pre, const float* __restrict__ b0,
    const float* __restrict__ b1, const float* __restrict__ W2,
    const float* __restrict__ b2, float* __restrict__ pred) {
  __shared__ __align__(16) char smem[163840];
  char* Wbuf = smem;             // 32 KB: one K-step of weights [slot][n][16B]
  char* Abuf = smem + 32768;     // 8 KB (GEMM1 A tile) — aliases h1 region
  char* Hc   = smem + 32768;     // 128 KB h1 [m][n], 16-quad XOR swizzle
  float* Pp  = (float*)smem;     // 12 KB partials (epilogue 2) — aliases Wbuf

  const int tid = threadIdx.x;
  const int wid = tid >> 6;
  const int lane = tid & 63;
  const int llo = lane & 15;
  const int lhi = lane >> 4;
  const int m0 = blockIdx.x * BM;
  const int swz = llo << 4;      // h1 swizzle: (m&15)<<4, and m&15 == llo

  // A staging ids: thread -> (row, k-chunk)
  const int arow = tid >> 2, ach = tid & 3;
  const float* aptr = feat + (size_t)(m0 + arow) * LATENT + ach * 8;

  // ---- prologue: load W step0 + A step0 into registers ----
  int4v wreg[4];
#pragma unroll
  for (int p = 0; p < 4; ++p) wreg[p] = *(const int4v*)(W0pre + p * 4096 + tid * 8);
  const ushort_t* wptr = W0pre + 16384;
  float4v a0 = *(const float4v*)(aptr);
  float4v a1 = *(const float4v*)(aptr + 4);

  f32x4 acc[4][8];
#pragma unroll
  for (int nt = 0; nt < 4; ++nt)
#pragma unroll
    for (int mt = 0; mt < 8; ++mt) acc[nt][mt] = 0.0f;

  // ================= GEMM1: h1' = W0^T x feat^T (8 K-steps) =================
  for (int t = 0; t < 8; ++t) {
    // write staged regs to LDS (previous step's frag reads done: trailing bar)
#pragma unroll
    for (int p = 0; p < 4; ++p) *(int4v*)(Wbuf + p * 8192 + tid * 16) = wreg[p];
    {
      unsigned u[4];
      u[0] = f2bf(a0[0]) | (f2bf(a0[1]) << 16);
      u[1] = f2bf(a0[2]) | (f2bf(a0[3]) << 16);
      u[2] = f2bf(a1[0]) | (f2bf(a1[1]) << 16);
      u[3] = f2bf(a1[2]) | (f2bf(a1[3]) << 16);
      *(int4v*)(Abuf + ach * 2048 + ((arow ^ (ach << 2)) * 16)) = *(int4v*)u;
    }
    // issue next-step global loads (hide L2/HBM latency under frag reads+MFMA)
    const ushort_t* ldp = (t == 7) ? W1pre : wptr;
#pragma unroll
    for (int p = 0; p < 4; ++p) wreg[p] = *(const int4v*)(ldp + p * 4096 + tid * 8);
    wptr = ldp + 16384;
    if (t < 7) {
      a0 = *(const float4v*)(aptr + (t + 1) * 32);
      a1 = *(const float4v*)(aptr + (t + 1) * 32 + 4);
    }
    __syncthreads();

    short8 wf[4], xf[8];
#pragma unroll
    for (int nt = 0; nt < 4; ++nt)
      wf[nt] = *(const short8*)(Wbuf + lhi * 8192 + (wid * 64 + nt * 16 + llo) * 16);
#pragma unroll
    for (int mt = 0; mt < 8; ++mt)
      xf[mt] = *(const short8*)(Abuf + lhi * 2048 + (((mt * 16 + llo) ^ (lhi << 2)) * 16));
#pragma unroll
    for (int nt = 0; nt < 4; ++nt)
#pragma unroll
      for (int mt = 0; mt < 8; ++mt)
        acc[nt][mt] = __builtin_amdgcn_mfma_f32_16x16x32_bf16(wf[nt], xf[mt], acc[nt][mt], 0, 0, 0);
    __syncthreads();
  }

  // ---- epilogue 1: h1 = silu(acc + b0) -> Hc (swizzled) ----
#pragma unroll
  for (int nt = 0; nt < 4; ++nt) {
    int nb = wid * 64 + nt * 16 + lhi * 4;
    float4v bv = *(const float4v*)(b0 + nb);
#pragma unroll
    for (int mt = 0; mt < 8; ++mt) {
      int m = mt * 16 + llo;
      uint2v pk;
      pk.x = f2bf(silu_f(acc[nt][mt][0] + bv[0])) | (f2bf(silu_f(acc[nt][mt][1] + bv[1])) << 16);
      pk.y = f2bf(silu_f(acc[nt][mt][2] + bv[2])) | (f2bf(silu_f(acc[nt][mt][3] + bv[3])) << 16);
      *(uint2v*)(Hc + m * 1024 + ((nb * 2) ^ swz)) = pk;
    }
  }
#pragma unroll
  for (int nt = 0; nt < 4; ++nt)
#pragma unroll
    for (int mt = 0; mt < 8; ++mt) acc[nt][mt] = 0.0f;

  // ================= GEMM2: h2' = W1^T x h1^T (16 K-steps) =================
  for (int t = 0; t < 16; ++t) {
#pragma unroll
    for (int p = 0; p < 4; ++p) *(int4v*)(Wbuf + p * 8192 + tid * 16) = wreg[p];
    if (t < 15) {
#pragma unroll
      for (int p = 0; p < 4; ++p) wreg[p] = *(const int4v*)(wptr + p * 4096 + tid * 8);
      wptr += 16384;
    }
    __syncthreads();

    short8 wf[4], xf[8];
#pragma unroll
    for (int nt = 0; nt < 4; ++nt)
      wf[nt] = *(const short8*)(Wbuf + lhi * 8192 + (wid * 64 + nt * 16 + llo) * 16);
#pragma unroll
    for (int mt = 0; mt < 8; ++mt)
      xf[mt] = *(const short8*)(Hc + (mt * 16 + llo) * 1024 + ((t * 64 + lhi * 16) ^ swz));
#pragma unroll
    for (int nt = 0; nt < 4; ++nt)
#pragma unroll
      for (int mt = 0; mt < 8; ++mt)
        acc[nt][mt] = __builtin_amdgcn_mfma_f32_16x16x32_bf16(wf[nt], xf[mt], acc[nt][mt], 0, 0, 0);
    __syncthreads();
  }

  // ---- epilogue 2: pred = silu(acc + b1) @ W2 + b2 ----
  float p[8][3];
#pragma unroll
  for (int mt = 0; mt < 8; ++mt) { p[mt][0] = 0.f; p[mt][1] = 0.f; p[mt][2] = 0.f; }
#pragma unroll
  for (int nt = 0; nt < 4; ++nt) {
    int nb = wid * 64 + nt * 16 + lhi * 4;
    float4v bv = *(const float4v*)(b1 + nb);
#pragma unroll
    for (int r = 0; r < 4; ++r) {
      float w20 = W2[(nb + r) * 3 + 0];
      float w21 = W2[(nb + r) * 3 + 1];
      float w22 = W2[(nb + r) * 3 + 2];
#pragma unroll
      for (int mt = 0; mt < 8; ++mt) {
        float h = silu_f(acc[nt][mt][r] + bv[r]);
        p[mt][0] += h * w20; p[mt][1] += h * w21; p[mt][2] += h * w22;
      }
    }
  }
#pragma unroll
  for (int mt = 0; mt < 8; ++mt)
#pragma unroll
    for (int o = 0; o < 3; ++o) {
      float v = p[mt][o];
      v += __shfl_xor(v, 16);
      v += __shfl_xor(v, 32);
      if (lane < 16) Pp[wid * 384 + (mt * 16 + llo) * 3 + o] = v;
    }
  __syncthreads();
  if (tid < 384) {
    float v = b2[tid % 3];
#pragma unroll
    for (int ww = 0; ww < 8; ++ww) v += Pp[ww * 384 + tid];
    pred[(size_t)m0 * 3 + tid] = v;
  }
}

// ---------------------------------------------------------------------------
// Per-graph finalize: mean removal + analytic torque removal. 1 block/graph.
// ---------------------------------------------------------------------------
template<int NV>
__device__ __forceinline__ void block_reduce(const float* v, float (*sc)[16], int wid, int lane,
                                             float* tot) {
#pragma unroll
  for (int j = 0; j < NV; ++j) {
    float x = v[j];
#pragma unroll
    for (int off = 32; off >= 1; off >>= 1) x += __shfl_down(x, off);
    if (lane == 0) sc[wid][j] = x;
  }
  __syncthreads();
#pragma unroll
  for (int j = 0; j < NV; ++j) tot[j] = sc[0][j] + sc[1][j] + sc[2][j] + sc[3][j];
  __syncthreads();
}

__global__ __launch_bounds__(256) void finalize_kernel(
    const float* __restrict__ pred, const float* __restrict__ pos,
    const float* __restrict__ cell, const int* __restrict__ n_node,
    float* __restrict__ out) {
  __shared__ float sc[4][16];
  int g = blockIdx.x, tid = threadIdx.x;
  int wid = tid >> 6, lane = tid & 63;
  size_t i = (size_t)g * NPG + tid;

  float p0 = pred[i * 3 + 0], p1 = pred[i * 3 + 1], p2 = pred[i * 3 + 2];
  float q0 = pos[i * 3 + 0], q1 = pos[i * 3 + 1], q2 = pos[i * 3 + 2];

  float v1[6] = {p0, p1, p2, q0, q1, q2};
  float t1[6];
  block_reduce<6>(v1, sc, wid, lane, t1);

  float cnt = (float)n_node[g];
  float pc0 = p0 - t1[0] / cnt, pc1 = p1 - t1[1] / cnt, pc2 = p2 - t1[2] / cnt;
  float r0 = q0 - t1[3] / cnt, r1 = q1 - t1[4] / cnt, r2 = q2 - t1[5] / cnt;

  float v2[10] = {r1 * pc2 - r2 * pc1, r2 * pc0 - r0 * pc2, r0 * pc1 - r1 * pc0,
                  r0 * r0 + r1 * r1 + r2 * r2,
                  r0 * r0, r0 * r1, r0 * r2, r1 * r1, r1 * r2, r2 * r2};
  float t2[10];
  block_reduce<10>(v2, sc, wid, lane, t2);

  double s = (double)t2[3];
  double a = (double)t2[4] - s, b = (double)t2[5], c = (double)t2[6];
  double d = (double)t2[7] - s, e = (double)t2[8], f = (double)t2[9] - s;
  double A00 = d * f - e * e;
  double A01 = c * e - b * f;
  double A02 = b * e - c * d;
  double A11 = a * f - c * c;
  double A12 = b * c - a * e;
  double A22 = a * d - b * b;
  double det = a * A00 + b * A01 + c * A02;
  double rinv = 1.0 / det;
  double rhs0 = -(double)t2[0], rhs1 = -(double)t2[1], rhs2 = -(double)t2[2];
  double mu0 = (A00 * rhs0 + A01 * rhs1 + A02 * rhs2) * rinv;
  double mu1 = (A01 * rhs0 + A11 * rhs1 + A12 * rhs2) * rinv;
  double mu2 = (A02 * rhs0 + A12 * rhs1 + A22 * rhs2) * rinv;

  bool nopbc = true;
#pragma unroll
  for (int j = 0; j < 9; ++j) nopbc = nopbc && (cell[g * 9 + j] == 0.0f);

  float d0 = (float)((double)r1 * mu2 - (double)r2 * mu1);
  float d1 = (float)((double)r2 * mu0 - (double)r0 * mu2);
  float d2 = (float)((double)r0 * mu1 - (double)r1 * mu0);

  out[i * 3 + 0] = pc0 + (nopbc ? d0 : 0.0f);
  out[i * 3 + 1] = pc1 + (nopbc ? d1 : 0.0f);
  out[i * 3 + 2] = pc2 + (nopbc ? d2 : 0.0f);
}

// ---------------------------------------------------------------------------
extern "C" void kernel_launch(void* const* d_in, const int* in_sizes, int n_in,
                              void* d_out, int out_size, void* d_ws, size_t ws_size,
                              hipStream_t stream) {
  const float* feat = (const float*)d_in[0];
  const float* positions = (const float*)d_in[1];
  const float* cell = (const float*)d_in[2];
  const int* n_node = (const int*)d_in[3];
  const float* W0 = (const float*)d_in[4];
  const float* b0 = (const float*)d_in[5];
  const float* W1 = (const float*)d_in[6];
  const float* b1 = (const float*)d_in[7];
  const float* W2 = (const float*)d_in[8];
  const float* b2 = (const float*)d_in[9];
  float* out = (float*)d_out;

  char* ws = (char*)d_ws;
  ushort_t* W0pre = (ushort_t*)ws;                       // 256 KB
  ushort_t* W1pre = (ushort_t*)(ws + 262144);            // 512 KB
  float* pred = (float*)(ws + 786432);                   // 3 MB

  hipLaunchKernelGGL(prep_weights, dim3(192), dim3(256), 0, stream, W0, W1, W0pre, W1pre);
  hipLaunchKernelGGL(fused_mlp, dim3(N_NODES / BM), dim3(512), 0, stream,
                     feat, W0pre, W1pre, b0, b1, W2, b2, pred);
  hipLaunchKernelGGL(finalize_kernel, dim3(BGRAPHS), dim3(256), 0, stream, pred, positions, cell,
                     n_node, out);
}